// Round 1
// baseline (433.545 us; speedup 1.0000x reference)
//
#include <hip/hip_runtime.h>
#include <hip/hip_bf16.h>

#define NN 262144
#define DD 256
#define HH 128
#define GG 2048

typedef __attribute__((ext_vector_type(8))) __bf16 bf16x8;
typedef __attribute__((ext_vector_type(4))) float f32x4;

union ABFrag { bf16x8 v; unsigned short u[8]; };
union BFrag  { bf16x8 v; uint4 i; };

__device__ __forceinline__ unsigned short f2bf(float f) {
    unsigned int u = __float_as_uint(f);
    unsigned int r = (u + 0x7fffu + ((u >> 16) & 1u)) >> 16;
    return (unsigned short)r;
}

// ---------------- kernel 0: W1 (fp32 [256][128]) -> W1T (bf16 [128][256]) ----
__global__ void prep_kernel(const float* __restrict__ w1, unsigned short* __restrict__ w1t) {
    int i = blockIdx.x * 256 + threadIdx.x;      // 0..32767 over W1T elements
    int n = i >> 8;                               // W1T row   (0..127)
    int k = i & 255;                              // W1T col   (0..255)
    w1t[i] = f2bf(w1[k * HH + n]);
}

// ---------------- kernel 1: scores = relu(x@W1+b1)@W2 + b2  (bf16 MFMA) -----
// Each wave: 64 rows (4 M-tiles of 16). K=256 in 8 steps of 32.
// A-frag: lane L holds x[row = base + (L&15)][k = (L>>4)*8 + j]
// B-frag: lane L holds W1T[n = t*16 + (L&15)][k = (L>>4)*8 + j]
// C/D:    lane L reg r -> row = (L>>4)*4 + r, col = (L&15)
__global__ __launch_bounds__(256, 2)
void scores_kernel(const float* __restrict__ x,
                   const unsigned short* __restrict__ w1t,
                   const float* __restrict__ b1,
                   const float* __restrict__ w2,
                   const float* __restrict__ b2,
                   float* __restrict__ scores)
{
    const int lane = threadIdx.x & 63;
    const int wv   = threadIdx.x >> 6;
    const int c = lane & 15;
    const int q = lane >> 4;
    const int rowBlock = blockIdx.x * 256 + wv * 64;

    float b1v[8], w2v[8];
#pragma unroll
    for (int t = 0; t < 8; ++t) { b1v[t] = b1[t * 16 + c]; w2v[t] = w2[t * 16 + c]; }
    const float b2s = b2[0];

    f32x4 acc[4][8];
#pragma unroll
    for (int it = 0; it < 4; ++it)
#pragma unroll
        for (int t = 0; t < 8; ++t) acc[it][t] = (f32x4){0.f, 0.f, 0.f, 0.f};

#pragma unroll
    for (int kk = 0; kk < 8; ++kk) {
        BFrag bf[8];
#pragma unroll
        for (int t = 0; t < 8; ++t) {
            const uint4* p = (const uint4*)(w1t + (size_t)(t * 16 + c) * DD + kk * 32 + q * 8);
            bf[t].i = *p;
        }
#pragma unroll
        for (int it = 0; it < 4; ++it) {
            const float* px = x + (size_t)(rowBlock + it * 16 + c) * DD + kk * 32 + q * 8;
            float4 f0 = *(const float4*)px;
            float4 f1 = *(const float4*)(px + 4);
            ABFrag af;
            af.u[0] = f2bf(f0.x); af.u[1] = f2bf(f0.y); af.u[2] = f2bf(f0.z); af.u[3] = f2bf(f0.w);
            af.u[4] = f2bf(f1.x); af.u[5] = f2bf(f1.y); af.u[6] = f2bf(f1.z); af.u[7] = f2bf(f1.w);
#pragma unroll
            for (int t = 0; t < 8; ++t)
                acc[it][t] = __builtin_amdgcn_mfma_f32_16x16x32_bf16(af.v, bf[t].v, acc[it][t], 0, 0, 0);
        }
    }

    // epilogue: + b1, relu, * W2, reduce over the 128 hidden dims
#pragma unroll
    for (int it = 0; it < 4; ++it) {
        float s0 = 0.f, s1 = 0.f, s2 = 0.f, s3 = 0.f;
#pragma unroll
        for (int t = 0; t < 8; ++t) {
            float w = w2v[t], bb = b1v[t];
            f32x4 a = acc[it][t];
            s0 += fmaxf(a.x + bb, 0.f) * w;
            s1 += fmaxf(a.y + bb, 0.f) * w;
            s2 += fmaxf(a.z + bb, 0.f) * w;
            s3 += fmaxf(a.w + bb, 0.f) * w;
        }
#pragma unroll
        for (int off = 1; off < 16; off <<= 1) {
            s0 += __shfl_xor(s0, off);
            s1 += __shfl_xor(s1, off);
            s2 += __shfl_xor(s2, off);
            s3 += __shfl_xor(s3, off);
        }
        if (c == 0) {
            float* o = scores + rowBlock + it * 16 + q * 4;
            o[0] = s0 + b2s; o[1] = s1 + b2s; o[2] = s2 + b2s; o[3] = s3 + b2s;
        }
    }
}

// ---------------- kernel 2: per-graph max & 1/sum(exp) -----------------------
__global__ void stats_kernel(const float* __restrict__ scores,
                             const int* __restrict__ batch,
                             float* __restrict__ gmax, float* __restrict__ ginv,
                             int* __restrict__ bstart, int* __restrict__ bend)
{
    int g = blockIdx.x;
    int lo = 0, hi = NN;
    while (lo < hi) { int mid = (lo + hi) >> 1; if (batch[mid] < g) lo = mid + 1; else hi = mid; }
    int start = lo;
    hi = NN;
    while (lo < hi) { int mid = (lo + hi) >> 1; if (batch[mid] < g + 1) lo = mid + 1; else hi = mid; }
    int end = lo;

    int lane = threadIdx.x;
    float m = -3.402823466e38f;
    for (int i = start + lane; i < end; i += 64) m = fmaxf(m, scores[i]);
#pragma unroll
    for (int off = 1; off < 64; off <<= 1) m = fmaxf(m, __shfl_xor(m, off));
    float sum = 0.f;
    for (int i = start + lane; i < end; i += 64) sum += __expf(scores[i] - m);
#pragma unroll
    for (int off = 1; off < 64; off <<= 1) sum += __shfl_xor(sum, off);
    if (lane == 0) {
        gmax[g] = m;
        ginv[g] = (end > start) ? 1.0f / sum : 0.0f;
        bstart[g] = start;
        bend[g] = end;
    }
}

// ---------------- kernel 3: weighted segment pooling -------------------------
__global__ __launch_bounds__(256)
void pool_kernel(const float* __restrict__ x, const float* __restrict__ scores,
                 const float* __restrict__ gmax, const float* __restrict__ ginv,
                 const int* __restrict__ bstart, const int* __restrict__ bend,
                 float* __restrict__ out)
{
    int g = blockIdx.x;
    int d = threadIdx.x;
    int start = bstart[g], end = bend[g];
    float m = gmax[g], inv = ginv[g];
    __shared__ float wl[256];
    float acc = 0.f;
    for (int base = start; base < end; base += 256) {
        int nch = min(256, end - base);
        __syncthreads();
        if (d < nch) wl[d] = __expf(scores[base + d] - m) * inv;
        __syncthreads();
        int j = 0;
        for (; j + 4 <= nch; j += 4) {
            const float* px = x + (size_t)(base + j) * DD + d;
            float x0 = px[0], x1 = px[DD], x2 = px[2 * DD], x3 = px[3 * DD];
            acc = fmaf(wl[j], x0, acc);
            acc = fmaf(wl[j + 1], x1, acc);
            acc = fmaf(wl[j + 2], x2, acc);
            acc = fmaf(wl[j + 3], x3, acc);
        }
        for (; j < nch; ++j) acc = fmaf(wl[j], x[(size_t)(base + j) * DD + d], acc);
    }
    out[(size_t)g * DD + d] = acc;
}

extern "C" void kernel_launch(void* const* d_in, const int* in_sizes, int n_in,
                              void* d_out, int out_size, void* d_ws, size_t ws_size,
                              hipStream_t stream) {
    const float* x     = (const float*)d_in[0];
    const int*   batch = (const int*)d_in[1];
    const float* W1    = (const float*)d_in[3];
    const float* b1    = (const float*)d_in[4];
    const float* W2    = (const float*)d_in[5];
    const float* b2    = (const float*)d_in[6];
    float* out = (float*)d_out;

    char* ws = (char*)d_ws;
    float*          scores = (float*)ws;                               // N fp32   (1 MB)
    unsigned short* w1t    = (unsigned short*)(ws + (size_t)NN * 4);   // 32768 bf16 (64 KB)
    float*          gmax   = (float*)(ws + (size_t)NN * 4 + 65536);    // G fp32
    float*          ginv   = gmax + GG;                                // G fp32
    int*            bstart = (int*)(ginv + GG);                        // G int
    int*            bend   = bstart + GG;                              // G int

    prep_kernel<<<HH * DD / 256, 256, 0, stream>>>(W1, w1t);
    scores_kernel<<<NN / 256, 256, 0, stream>>>(x, w1t, b1, W2, b2, scores);
    stats_kernel<<<GG, 64, 0, stream>>>(scores, batch, gmax, ginv, bstart, bend);
    pool_kernel<<<GG, 256, 0, stream>>>(x, scores, gmax, ginv, bstart, bend, out);
}